// Round 1
// 195.738 us; speedup vs baseline: 1.0325x; 1.0325x over previous
//
#include <hip/hip_runtime.h>

#define NF   20000
#define NALL 60000
#define NE   640000
#define DD   128
#define AA   64

typedef __attribute__((ext_vector_type(8))) short short8;
typedef __attribute__((ext_vector_type(4))) float f32x4;

__device__ __forceinline__ unsigned short f2b(float x) {
    unsigned int u = __float_as_uint(x);
    return (unsigned short)((u + 0x7FFFu + ((u >> 16) & 1u)) >> 16);  // RNE
}
__device__ __forceinline__ float b2f(unsigned short v) {
    return __uint_as_float(((unsigned int)v) << 16);
}
__device__ __forceinline__ short8 pack8(float4 a, float4 b) {
    short8 r;
    r[0]=(short)f2b(a.x); r[1]=(short)f2b(a.y); r[2]=(short)f2b(a.z); r[3]=(short)f2b(a.w);
    r[4]=(short)f2b(b.x); r[5]=(short)f2b(b.y); r[6]=(short)f2b(b.z); r[7]=(short)f2b(b.w);
    return r;
}

// ---- K1: fused conv+proj. Loads fp32 embs, converts (writes embB bf16),
// computes P1 = feat@W1+bias, P2 = [feat;hid]@W2 (bf16) via MFMA. W from fp32 on the fly.
__global__ __launch_bounds__(256) void embproj_kernel(
    const float* __restrict__ featEmb, const float* __restrict__ hidEmb,
    const float* __restrict__ wK, const float* __restrict__ bias,
    unsigned short* __restrict__ embB,
    unsigned short* __restrict__ P1b, unsigned short* __restrict__ P2b)
{
    const int wave = threadIdx.x >> 6, lane = threadIdx.x & 63;
    const int rt = blockIdx.x * 4 + wave;
    if (rt >= NALL / 16) return;
    const int row0 = rt * 16;
    const int m = lane & 15, quad = lane >> 4;

    const int row = row0 + m;   // NF % 16 == 0: no tile straddles the feat/hid boundary
    const float* src = (row < NF) ? featEmb + (size_t)row * DD
                                  : hidEmb + (size_t)(row - NF) * DD;
    short8 afr[4];
    #pragma unroll
    for (int kc = 0; kc < 4; ++kc) {
        float4 a0 = *(const float4*)&src[kc * 32 + quad * 8];
        float4 a1 = *(const float4*)&src[kc * 32 + quad * 8 + 4];
        afr[kc] = pack8(a0, a1);
        *(short8*)&embB[(size_t)row * DD + kc * 32 + quad * 8] = afr[kc];
    }

    const float* W2 = wK + DD * AA;   // rows 128..255 of w_kernel
    #pragma unroll
    for (int nt = 0; nt < 4; ++nt) {
        f32x4 acc = {0.f, 0.f, 0.f, 0.f};
        #pragma unroll
        for (int kc = 0; kc < 4; ++kc) {
            short8 bfr;
            #pragma unroll
            for (int j = 0; j < 8; ++j)
                bfr[j] = (short)f2b(W2[(kc * 32 + quad * 8 + j) * AA + nt * 16 + m]);
            acc = __builtin_amdgcn_mfma_f32_16x16x32_bf16(afr[kc], bfr, acc, 0, 0, 0);
        }
        #pragma unroll
        for (int r = 0; r < 4; ++r)   // C/D: col=lane&15, row=quad*4+r
            P2b[(size_t)(row0 + quad * 4 + r) * AA + nt * 16 + m] = f2b(acc[r]);
    }
    if (row0 < NF) {
        #pragma unroll
        for (int nt = 0; nt < 4; ++nt) {
            f32x4 acc = {0.f, 0.f, 0.f, 0.f};
            #pragma unroll
            for (int kc = 0; kc < 4; ++kc) {
                short8 bfr;
                #pragma unroll
                for (int j = 0; j < 8; ++j)
                    bfr[j] = (short)f2b(wK[(kc * 32 + quad * 8 + j) * AA + nt * 16 + m]);
                acc = __builtin_amdgcn_mfma_f32_16x16x32_bf16(afr[kc], bfr, acc, 0, 0, 0);
            }
            const float bv = bias[nt * 16 + m];
            #pragma unroll
            for (int r = 0; r < 4; ++r)
                P1b[(size_t)(row0 + quad * 4 + r) * AA + nt * 16 + m] = f2b(acc[r] + bv);
        }
    }
}

// ---- K2: rowptr[f] = lower_bound(cp, f). Boundary scatter, cp sorted.
__global__ __launch_bounds__(256) void rowptr_kernel(
    const int* __restrict__ cp, int* __restrict__ rowptr)
{
    const int e = blockIdx.x * 256 + threadIdx.x;
    const int cur = cp[e];
    const int prev = (e == 0) ? -1 : cp[e - 1];
    for (int f = prev + 1; f <= cur; ++f) rowptr[f] = e;
    if (e == NE - 1)
        for (int f = cur + 1; f <= NF; ++f) rowptr[f] = NE;
}

// ---- K3: scores. 256 connections/block; P2 rows staged via LDS (1 line/row).
__global__ __launch_bounds__(256) void score_kernel(
    const unsigned short* __restrict__ P1b, const unsigned short* __restrict__ P2b,
    const float* __restrict__ uK, const float* __restrict__ corr,
    const int* __restrict__ cp, const int* __restrict__ fci,
    float* __restrict__ scores)
{
    __shared__ unsigned int sp2[256 * 33];   // stride 33 dwords: (t+c)%32 banks, 2-way free
    __shared__ int sidx[256];
    __shared__ float su[AA];
    const int t = threadIdx.x;
    const int e0 = blockIdx.x * 256;

    sidx[t] = fci[e0 + t];
    if (t < AA) su[t] = uK[t];
    __syncthreads();

    const int h = t >> 5, l = t & 31;   // half-wave loads one row (=1 cacheline) per iter
    #pragma unroll 4
    for (int i = 0; i < 32; ++i) {
        const int r = i * 8 + h;
        const int row = sidx[r];
        sp2[r * 33 + l] = *(const unsigned int*)&P2b[(size_t)row * AA + l * 2];
    }
    __syncthreads();

    const int e = e0 + t;
    const unsigned short* p1 = P1b + (size_t)cp[e] * AA;  // ~8 distinct rows/block: L1-hot
    float s = 0.f;
    #pragma unroll
    for (int c = 0; c < 8; ++c) {
        short8 a = *(const short8*)&p1[c * 8];
        #pragma unroll
        for (int d = 0; d < 4; ++d) {
            const unsigned int v = sp2[t * 33 + c * 4 + d];
            const float x0 = b2f((unsigned short)a[d * 2])     + b2f((unsigned short)(v & 0xFFFF));
            const float x1 = b2f((unsigned short)a[d * 2 + 1]) + b2f((unsigned short)(v >> 16));
            const float t0 = 1.f - 2.f * __builtin_amdgcn_rcpf(__expf(2.f * x0) + 1.f);
            const float t1 = 1.f - 2.f * __builtin_amdgcn_rcpf(__expf(2.f * x1) + 1.f);
            s = fmaf(t0, su[c * 8 + d * 2], s);
            s = fmaf(t1, su[c * 8 + d * 2 + 1], s);
        }
    }
    scores[e] = __expf(s) * corr[e];
}

// ---- K4: segment softmax + context -> ctxT bf16 [128][20000].
// 32 consecutive features per block (= one full 64B line per ctxT row), 16 waves,
// 2 features/wave. Register accumulate -> LDS transpose tile -> full-line stores.
// Kills the 9x partial-line write amplification (RMW fetch+writeback) of the
// old 1-feature-per-wave transposed store.
__global__ __launch_bounds__(1024, 8) void ctx_kernel(
    const unsigned short* __restrict__ embB,
    const float* __restrict__ scores,
    const int* __restrict__ rowptr, const int* __restrict__ fci,
    unsigned short* __restrict__ ctxT)
{
    __shared__ unsigned int tile[64 * 33];   // [dpair][feat]: lo16=row 2d, hi16=row 2d+1
    const int lane = threadIdx.x & 63;
    const int wave = threadIdx.x >> 6;       // 0..15
    const int f0 = blockIdx.x * 32;

    #pragma unroll
    for (int sub = 0; sub < 2; ++sub) {
        const int fl = wave * 2 + sub;
        const int f = f0 + fl;
        const int start = rowptr[f], end = rowptr[f + 1];

        float acc0 = 0.f, acc1 = 0.f, den = 0.f;
        int e = start;
        for (; e + 8 <= end; e += 8) {   // 8 independent row gathers in flight
            int   ii[8]; float ss[8]; unsigned int vv[8];
            #pragma unroll
            for (int j = 0; j < 8; ++j) ii[j] = fci[e + j];
            #pragma unroll
            for (int j = 0; j < 8; ++j) ss[j] = scores[e + j];
            #pragma unroll
            for (int j = 0; j < 8; ++j)
                vv[j] = *(const unsigned int*)&embB[(size_t)ii[j] * DD + lane * 2];
            #pragma unroll
            for (int j = 0; j < 8; ++j) {
                acc0 = fmaf(ss[j], b2f((unsigned short)(vv[j] & 0xFFFF)), acc0);
                acc1 = fmaf(ss[j], b2f((unsigned short)(vv[j] >> 16)),    acc1);
                den += ss[j];
            }
        }
        for (; e < end; ++e) {
            const int i0 = fci[e]; const float s0 = scores[e];
            const unsigned int v0 = *(const unsigned int*)&embB[(size_t)i0 * DD + lane * 2];
            acc0 = fmaf(s0, b2f((unsigned short)(v0 & 0xFFFF)), acc0);
            acc1 = fmaf(s0, b2f((unsigned short)(v0 >> 16)),    acc1);
            den += s0;
        }
        const float inv = (den != 0.f) ? 1.f / den : 0.f;
        // banks: (lane*33+fl)%32 = (lane%32 + fl)%32 -> 2-way per wave store = free
        tile[lane * 33 + fl] = ((unsigned int)f2b(acc1 * inv) << 16) | f2b(acc0 * inv);
    }
    __syncthreads();

    // Write phase: 2048 u32 in tile, 1024 threads -> 2 cols of one dpair each.
    // 16 consecutive threads cover one full 64B line of a ctxT row.
    const int dpair = threadIdx.x >> 4;      // 0..63
    const int seg   = threadIdx.x & 15;      // 0..15
    const unsigned int v0 = tile[dpair * 33 + 2 * seg];      // col f0+2*seg
    const unsigned int v1 = tile[dpair * 33 + 2 * seg + 1];  // col f0+2*seg+1
    const unsigned int lo = (v1 << 16) | (v0 & 0xFFFFu);         // row 2*dpair
    const unsigned int hi = (v1 & 0xFFFF0000u) | (v0 >> 16);     // row 2*dpair+1
    *(unsigned int*)&ctxT[(size_t)(2 * dpair)     * NF + f0 + 2 * seg] = lo;
    *(unsigned int*)&ctxT[(size_t)(2 * dpair + 1) * NF + f0 + 2 * seg] = hi;
}

// ---- K5: out[256,128] = values @ ctx via MFMA; values split hi/lo bf16 (exact).
__global__ __launch_bounds__(256) void outmm_kernel(
    const float* __restrict__ values, const unsigned short* __restrict__ ctxT,
    float* __restrict__ out)
{
    const int wave = threadIdx.x >> 6, lane = threadIdx.x & 63;
    const int m = lane & 15, quad = lane >> 4;
    const int mgroup = blockIdx.x & 3, kchunk = blockIdx.x >> 2;
    const int m0 = mgroup * 64 + wave * 16;
    const int k0 = kchunk * 160;

    f32x4 acc[8];
    #pragma unroll
    for (int nt = 0; nt < 8; ++nt) acc[nt] = (f32x4){0.f, 0.f, 0.f, 0.f};

    for (int ks = 0; ks < 5; ++ks) {
        const int kk = k0 + ks * 32 + quad * 8;
        const float* ap = &values[(size_t)(m0 + m) * NF + kk];
        float4 a0 = *(const float4*)ap;
        float4 a1 = *(const float4*)(ap + 4);
        float av[8] = {a0.x, a0.y, a0.z, a0.w, a1.x, a1.y, a1.z, a1.w};
        short8 ahi, alo;
        #pragma unroll
        for (int j = 0; j < 8; ++j) {
            unsigned short hv = f2b(av[j]);
            ahi[j] = (short)hv;
            alo[j] = (short)f2b(av[j] - b2f(hv));
        }
        #pragma unroll
        for (int nt = 0; nt < 8; ++nt) {
            short8 b = *(const short8*)&ctxT[(size_t)(nt * 16 + m) * NF + kk];
            acc[nt] = __builtin_amdgcn_mfma_f32_16x16x32_bf16(ahi, b, acc[nt], 0, 0, 0);
            acc[nt] = __builtin_amdgcn_mfma_f32_16x16x32_bf16(alo, b, acc[nt], 0, 0, 0);
        }
    }
    #pragma unroll
    for (int nt = 0; nt < 8; ++nt)
        #pragma unroll
        for (int r = 0; r < 4; ++r)
            atomicAdd(&out[(size_t)(m0 + quad * 4 + r) * DD + nt * 16 + m], acc[nt][r]);
}

extern "C" void kernel_launch(void* const* d_in, const int* in_sizes, int n_in,
                              void* d_out, int out_size, void* d_ws, size_t ws_size,
                              hipStream_t stream)
{
    const float* values  = (const float*)d_in[0];
    const float* featEmb = (const float*)d_in[1];
    const float* hidEmb  = (const float*)d_in[2];
    const float* wK      = (const float*)d_in[3];
    const float* wB      = (const float*)d_in[4];
    const float* uK      = (const float*)d_in[5];
    const float* corr    = (const float*)d_in[6];
    const int* cp        = (const int*)d_in[7];
    const int* fci       = (const int*)d_in[8];
    float* out = (float*)d_out;

    // ws layout (bytes, 16B-aligned):
    char* ws = (char*)d_ws;
    unsigned short* embB  = (unsigned short*)(ws);                   // 15,360,000
    unsigned short* P1b   = (unsigned short*)(ws + 15360000);        //  2,560,000
    unsigned short* P2b   = (unsigned short*)(ws + 17920000);        //  7,680,000
    float*          scr   = (float*)        (ws + 25600000);         //  2,560,000
    unsigned short* ctxT  = (unsigned short*)(ws + 28160000);        //  5,120,000
    int*            rowptr= (int*)          (ws + 33280000);         //     80,004  (total 33.4 MB)

    embproj_kernel<<<938,  256, 0, stream>>>(featEmb, hidEmb, wK, wB, embB, P1b, P2b);
    rowptr_kernel <<<2500, 256, 0, stream>>>(cp, rowptr);
    score_kernel  <<<2500, 256, 0, stream>>>(P1b, P2b, uK, corr, cp, fci, scr);
    ctx_kernel    <<<625, 1024, 0, stream>>>(embB, scr, rowptr, fci, ctxT);
    hipMemsetAsync(d_out, 0, (size_t)out_size * sizeof(float), stream);
    outmm_kernel  <<<500,  256, 0, stream>>>(values, ctxT, out);
}